// Round 2
// baseline (306.748 us; speedup 1.0000x reference)
//
#include <hip/hip_runtime.h>
#include <stdint.h>

typedef __attribute__((ext_vector_type(8))) short short8;
typedef __attribute__((ext_vector_type(4))) short short4v;
typedef __attribute__((ext_vector_type(4))) float floatx4;
typedef __attribute__((ext_vector_type(4))) _Float16 half4;
typedef __attribute__((ext_vector_type(2))) __fp16 pk2;

#define SEQ 2048
#define NTOK 8192
// 0.25 * log2(e): folds the 1/sqrt(H) quirk-scale and exp->exp2 into Q proj.
#define QSCALE 0.360673760222241f

#define MFMA16F16(a,b,c) __builtin_amdgcn_mfma_f32_16x16x16f16((a),(b),(c),0,0,0)

__device__ __forceinline__ float b2f(unsigned short u){
  union { unsigned int i; float f; } v; v.i = ((unsigned int)u) << 16; return v.f;
}
__device__ __forceinline__ unsigned short f2b(float f){
  union { float f; unsigned int i; } v; v.f = f;
  unsigned int r = v.i + 0x7fffu + ((v.i >> 16) & 1u);
  return (unsigned short)(r >> 16);
}
// async global->LDS, 16B per lane. Dest = wave-uniform base + lane*16.
__device__ __forceinline__ void async16(const unsigned short* g, unsigned short* l){
  __builtin_amdgcn_global_load_lds(
      (const __attribute__((address_space(1))) unsigned int*)g,
      (__attribute__((address_space(3))) unsigned int*)l, 16, 0, 0);
}

// ---------- fused prep: convert_x | transpose_w | bias_concat --------------
__global__ __launch_bounds__(256) void prep_kernel(
    const float* __restrict__ x,
    const float* __restrict__ wq, const float* __restrict__ wk,
    const float* __restrict__ wv, const float* __restrict__ wo,
    const float* __restrict__ bq, const float* __restrict__ bk,
    const float* __restrict__ bv,
    unsigned short* __restrict__ xb,
    unsigned short* __restrict__ wqkvT, unsigned short* __restrict__ woT,
    float* __restrict__ bqkv)
{
  __shared__ unsigned short lT[64][72];
  const int bid = blockIdx.x;
  const int tid = threadIdx.x;
  if (bid < 8192){
    int i = (bid*256 + tid)*4;
    float4 v = *(const float4*)(x + i);
    short4v o;
    o[0] = (short)f2b(v.x); o[1] = (short)f2b(v.y);
    o[2] = (short)f2b(v.z); o[3] = (short)f2b(v.w);
    *(short4v*)(xb + i) = o;
  } else if (bid < 9216){
    int idx = bid - 8192;
    int sel = idx >> 8, rest = idx & 255;
    const float* src = (sel==0)?wq:(sel==1)?wk:(sel==2)?wv:wo;
    unsigned short* dst = (sel<3) ? (wqkvT + (size_t)sel*1024*1024) : woT;
    int n0 = (rest & 15) * 64, k0 = (rest >> 4) * 64;
#pragma unroll
    for (int i=0;i<4;i++){
      int ch = tid + i*256;
      int r = ch>>4, c = (ch&15)*4;
      float4 v = *(const float4*)(src + (size_t)(k0+r)*1024 + n0 + c);
      lT[r][c+0] = f2b(v.x); lT[r][c+1] = f2b(v.y);
      lT[r][c+2] = f2b(v.z); lT[r][c+3] = f2b(v.w);
    }
    __syncthreads();
#pragma unroll
    for (int i=0;i<2;i++){
      int ch = tid + i*256;
      int rn = ch>>3, c = (ch&7)*8;
      short8 v;
#pragma unroll
      for (int j=0;j<8;j++) v[j] = (short)lT[c+j][rn];
      *(short8*)(dst + (size_t)(n0+rn)*1024 + k0 + c) = v;
    }
  } else {
    int i = (bid - 9216)*256 + tid;
    if (i < 3072){
      int sel = i >> 10, j = i & 1023;
      bqkv[i] = (sel==0)?bq[j]:(sel==1)?bk[j]:bv[j];
    }
  }
}

// ---------------- GEMM: C(MxN) = A(MxK) @ Bt(NxK)^T + bias ----------------
// MODE 1: f32 store. MODE 3: QKV fused — cols<1024 bf16*QSCALE, 1024..2047
// bf16, >=2048 (V) written f16 TRANSPOSED into Vt[(b*16+h)*64+dv][s]
// (fuses the old transpose_v kernel into the epilogue; V never hits qkvbuf).
template<int MODE>
__global__ __launch_bounds__(256) void gemm_bt_kernel(
    const unsigned short* __restrict__ A,
    const unsigned short* __restrict__ Bt,
    const float* __restrict__ bias,
    void* __restrict__ Cv,
    unsigned short* __restrict__ Vt,
    int M, int N, int K)
{
  __shared__ unsigned short lA[128*64];
  __shared__ unsigned short lB[128*64];
  const int tid  = threadIdx.x;
  const int lane = tid & 63;
  const int wave = tid >> 6;
  const int quad = lane >> 4;
  const int l15  = lane & 15;
  const int wR = (wave >> 1) * 64;
  const int wC = (wave & 1) * 64;
  const int rowB = blockIdx.y * 128;
  const int colB = blockIdx.x * 128;

  const int srow = wave*32 + (lane>>3);
  const int sc8  = (lane&7) ^ (lane>>3);
  const unsigned short* gA = A  + (size_t)(rowB + srow)*K + sc8*8;
  const unsigned short* gB = Bt + (size_t)(colB + srow)*K + sc8*8;
  unsigned short* lAw = lA + wave*32*64 + lane*8;
  unsigned short* lBw = lB + wave*32*64 + lane*8;

  floatx4 acc[4][4];
#pragma unroll
  for (int t=0;t<4;t++)
#pragma unroll
    for (int u=0;u<4;u++) acc[t][u] = (floatx4){0.f,0.f,0.f,0.f};

  for (int kt = 0; kt < K; kt += 64){
    __syncthreads();
#pragma unroll
    for (int i=0;i<4;i++){
      async16(gA + (size_t)i*8*K + kt, lAw + i*512);
      async16(gB + (size_t)i*8*K + kt, lBw + i*512);
    }
    __syncthreads();
#pragma unroll
    for (int ks=0; ks<2; ks++){
      const int cph = ((ks*4 + quad) ^ (l15 & 7)) * 8;
      short8 af[4], bf[4];
#pragma unroll
      for (int t=0;t<4;t++) af[t] = *(const short8*)&lA[(wR + t*16 + l15)*64 + cph];
#pragma unroll
      for (int u=0;u<4;u++) bf[u] = *(const short8*)&lB[(wC + u*16 + l15)*64 + cph];
#pragma unroll
      for (int t=0;t<4;t++)
#pragma unroll
        for (int u=0;u<4;u++)
          acc[t][u] = __builtin_amdgcn_mfma_f32_16x16x32_bf16(af[t], bf[u], acc[t][u], 0, 0, 0);
    }
  }
  // epilogue: C/D layout col = lane&15, row = quad*4 + r  [m89/m91 verified]
  if (MODE == 3 && colB >= 2048){
    // V block: transposed f16 store, 4 consecutive tokens per 8B chunk
#pragma unroll
    for (int u=0;u<4;u++){
      int col = colB + wC + u*16 + l15;
      float bval = bias[col];
      int vcol = col - 2048;
      int hh = vcol >> 6, dv = vcol & 63;
#pragma unroll
      for (int t=0;t<4;t++){
        int row0 = rowB + wR + t*16 + quad*4;       // token of acc[t][u][0]
        int bb = row0 >> 11, s = row0 & 2047;
        union { pk2 p[2]; short4v s4; } cv;
        cv.p[0] = __builtin_amdgcn_cvt_pkrtz(acc[t][u][0]+bval, acc[t][u][1]+bval);
        cv.p[1] = __builtin_amdgcn_cvt_pkrtz(acc[t][u][2]+bval, acc[t][u][3]+bval);
        *(short4v*)(Vt + ((size_t)(bb*16+hh)*64 + dv)*2048 + s) = cv.s4;
      }
    }
  } else {
#pragma unroll
    for (int u=0;u<4;u++){
      int col = colB + wC + u*16 + l15;
      float bval = bias[col];
      float scale = (MODE == 3 && col < 1024) ? QSCALE : 1.0f;
#pragma unroll
      for (int t=0;t<4;t++){
        int row0 = rowB + wR + t*16 + quad*4;
#pragma unroll
        for (int r=0;r<4;r++){
          float val = (acc[t][u][r] + bval) * scale;
          if (MODE == 1) ((float*)Cv)[(size_t)(row0 + r)*N + col] = val;
          else ((unsigned short*)Cv)[(size_t)(row0 + r)*N + col] = f2b(val);
        }
      }
    }
  }
}

// ---------------- flash attention forward, S^T formulation -----------------
// KV tile = 128 staged per barrier pair (two 64-row compute halves). Register
// prefetch of next tile during compute (measured-best staging).
//
// Round-2 revision (post-mortem of x32-PV experiment):
//  * PV back to mfma_f32_16x16x16f16: its A-frag layout (k = quad*4+j) is an
//    EXACT match for the S^T epilogue layout, so P feeds PV with zero
//    cross-lane movement. (The x32 route cost 32 shfl + ~100 cndmask per
//    iter on the critical S->exp2->PV chain: measured −15us regression.)
//  * KEEP the round-1 LDS layout: unpadded [64][64], 16B-chunk XOR swizzle
//    (chunk ^= row&7) on K and V — hardware-verified ZERO bank conflicts
//    (was 1.05e7 conflict cycles with pad-72 + sigma permute).
//    PV B-frags become per-u b64 reads at the swizzled offset; 32-lane
//    phase analysis: 2 lanes/bank-pair = free (m136).
//  * s_setprio(1) around MFMA bursts (T5): each SIMD hosts waves of 4
//    DIFFERENT blocks here (not barrier-lockstepped) — the regime where
//    attn setprio measured +4-7% (m191).
__global__ __launch_bounds__(256) void flash_attn_kernel(
    const unsigned short* __restrict__ qkv,
    const unsigned short* __restrict__ vt,      // f16 bits, [bh*64+dv][token]
    unsigned short* __restrict__ attn_out)      // bf16
{
  __shared__ __align__(16) unsigned short sK [2][64][64];  // bf16 [half][kv][dk]
  __shared__ __align__(16) unsigned short sVt[2][64][64];  // f16  [half][dv][kv]
  const int bh = blockIdx.x;
  const int b = bh >> 4, h = bh & 15;
  const int qt = blockIdx.y;
  const int tid = threadIdx.x;
  const int wave = tid >> 6;
  const int lane = tid & 63;
  const int quad = lane >> 4, l15 = lane & 15;
  const int tok0 = b*SEQ + qt*128;

  // Q B-fragments straight from global (n = q = l15, k contiguous)
  short8 qf[2][2];
#pragma unroll
  for (int t=0;t<2;t++)
#pragma unroll
    for (int ks=0;ks<2;ks++)
      qf[t][ks] = *(const short8*)(qkv + (size_t)(tok0 + wave*32 + t*16 + l15)*3072
                                   + h*64 + ks*32 + quad*8);

  floatx4 oacc[2][4];
  float psum[2] = {0.f, 0.f};
#pragma unroll
  for (int t=0;t<2;t++)
#pragma unroll
    for (int v=0;v<4;v++) oacc[t][v] = (floatx4){0.f,0.f,0.f,0.f};

  // staging geometry: 4 chunks/thread; chunk i: half HF=i>>1, row R, col C.
  // LDS col chunk XOR-swizzled by row&7 (conflict-free, HW-verified r1).
  int R[4], C[4], HF[4], SW[4];
#pragma unroll
  for (int i=0;i<4;i++){
    int chh = tid + (i&1)*256;
    R[i] = chh >> 3; C[i] = (chh & 7)*8; HF[i] = i >> 1;
    SW[i] = (((chh & 7) ^ (R[i] & 7)) * 8);
  }
  short8 rk[4], rv[4];
  // prefetch tile 0
#pragma unroll
  for (int i=0;i<4;i++){
    rk[i] = *(const short8*)(qkv + (size_t)(b*SEQ + HF[i]*64 + R[i])*3072 + 1024 + h*64 + C[i]);
    rv[i] = *(const short8*)(vt  + (size_t)(bh*64 + R[i])*2048 + HF[i]*64 + C[i]);
  }

  for (int it = 0; it < SEQ/128; it++){
    __syncthreads();
#pragma unroll
    for (int i=0;i<4;i++){
      *(short8*)&sK [HF[i]][R[i]][SW[i]] = rk[i];
      *(short8*)&sVt[HF[i]][R[i]][SW[i]] = rv[i];
    }
    __syncthreads();
    if (it + 1 < SEQ/128){             // prefetch next 128-KV tile
      int nx = (it + 1) * 128;
#pragma unroll
      for (int i=0;i<4;i++){
        rk[i] = *(const short8*)(qkv + (size_t)(b*SEQ + nx + HF[i]*64 + R[i])*3072 + 1024 + h*64 + C[i]);
        rv[i] = *(const short8*)(vt  + (size_t)(bh*64 + R[i])*2048 + nx + HF[i]*64 + C[i]);
      }
    }

#pragma unroll
    for (int hf=0; hf<2; hf++){
      // S^T[kv][q]: A = K (m=kv), B = Q (n=q). C: row=kv local, col=q=l15.
      floatx4 sacc[4][2];
#pragma unroll
      for (int u=0;u<4;u++)
#pragma unroll
        for (int t=0;t<2;t++) sacc[u][t] = (floatx4){0.f,0.f,0.f,0.f};
#pragma unroll
      for (int ks=0;ks<2;ks++){
        short8 kf[4];
#pragma unroll
        for (int u=0;u<4;u++)
          kf[u] = *(const short8*)&sK[hf][u*16 + l15][((ks*4 + quad) ^ (l15 & 7)) * 8];
        __builtin_amdgcn_s_setprio(1);
#pragma unroll
        for (int u=0;u<4;u++)
#pragma unroll
          for (int t=0;t<2;t++)
            sacc[u][t] = __builtin_amdgcn_mfma_f32_16x16x32_bf16(kf[u], qf[t][ks], sacc[u][t], 0,0,0);
        __builtin_amdgcn_s_setprio(0);
      }

      // p = 2^s in-register; pack to f16 A-frags (k local = quad*4 + r):
      // x16 A-frag layout matches the S^T epilogue EXACTLY — no routing.
      half4 pf[4][2];
#pragma unroll
      for (int t=0;t<2;t++){
#pragma unroll
        for (int u=0;u<4;u++){
          float p0 = __builtin_amdgcn_exp2f(sacc[u][t][0]);
          float p1 = __builtin_amdgcn_exp2f(sacc[u][t][1]);
          float p2 = __builtin_amdgcn_exp2f(sacc[u][t][2]);
          float p3 = __builtin_amdgcn_exp2f(sacc[u][t][3]);
          psum[t] += (p0+p1)+(p2+p3);
          union { pk2 p2v[2]; half4 h4; } cv;
          cv.p2v[0] = __builtin_amdgcn_cvt_pkrtz(p0,p1);
          cv.p2v[1] = __builtin_amdgcn_cvt_pkrtz(p2,p3);
          pf[u][t] = cv.h4;
        }
      }

      // O[q][dv] += P V : B-frag = V[kv=u*16+quad*4+j][dv=v*16+l15],
      // read as b64 from swizzled sVt (element col u*16+quad*4 ->
      // chunk 2u+(quad>>1), half quad&1; chunk XOR row&7 = l15&7).
#pragma unroll
      for (int v=0;v<4;v++){
        half4 vf[4];
#pragma unroll
        for (int u=0;u<4;u++)
          vf[u] = *(const half4*)&sVt[hf][v*16 + l15]
                    [(((2*u + (quad>>1)) ^ (l15 & 7)) << 3) + (quad & 1)*4];
        __builtin_amdgcn_s_setprio(1);
#pragma unroll
        for (int t=0;t<2;t++)
#pragma unroll
          for (int u=0;u<4;u++)
            oacc[t][v] = MFMA16F16(pf[u][t], vf[u], oacc[t][v]);
        __builtin_amdgcn_s_setprio(0);
      }
    }
  }

  // final row-sum reduction: quads sharing l15 hold partials for q=l15
#pragma unroll
  for (int t=0;t<2;t++){
    float s = psum[t];
    s += __shfl_xor(s, 16);
    s += __shfl_xor(s, 32);
    psum[t] = s;
  }
  // epilogue: O rows are q local = quad*4+r; lsum for that q lives at lane q
#pragma unroll
  for (int t=0;t<2;t++){
#pragma unroll
    for (int r=0;r<4;r++){
      float inv = 1.0f / __shfl(psum[t], quad*4 + r);
      int tok = tok0 + wave*32 + t*16 + quad*4 + r;
#pragma unroll
      for (int v=0;v<4;v++)
        attn_out[(size_t)tok*1024 + h*64 + v*16 + l15] = f2b(oacc[t][v][r] * inv);
    }
  }
}

extern "C" void kernel_launch(void* const* d_in, const int* in_sizes, int n_in,
                              void* d_out, int out_size, void* d_ws, size_t ws_size,
                              hipStream_t stream)
{
  const float* x  = (const float*)d_in[0];
  const float* wq = (const float*)d_in[1];
  const float* bq = (const float*)d_in[2];
  const float* wk = (const float*)d_in[3];
  const float* bk = (const float*)d_in[4];
  const float* wv = (const float*)d_in[5];
  const float* bv = (const float*)d_in[6];
  const float* wo = (const float*)d_in[7];
  const float* bo = (const float*)d_in[8];
  float* out = (float*)d_out;

  char* ws = (char*)d_ws;
  unsigned short* wqkvT  = (unsigned short*)(ws);               // 3072x1024 bf16
  unsigned short* woT    = (unsigned short*)(ws + 6291456);     // 1024x1024 bf16
  float*          bqkv   = (float*)(ws + 8388608);              // 3072 f32
  unsigned short* xb     = (unsigned short*)(ws + 8400896);     // 8192x1024 bf16
  unsigned short* qkvbuf = (unsigned short*)(ws + 25178112);    // 8192x3072 bf16 (V region unused)
  unsigned short* vtbuf  = (unsigned short*)(ws + 75509760);    // 4096x2048 f16
  unsigned short* aobuf  = (unsigned short*)(ws + 92286976);    // 8192x1024 bf16

  prep_kernel<<<dim3(9228), 256, 0, stream>>>(x, wq, wk, wv, wo, bq, bk, bv,
                                              xb, wqkvT, woT, bqkv);
  gemm_bt_kernel<3><<<dim3(24, 64), 256, 0, stream>>>(xb, wqkvT, bqkv, qkvbuf, vtbuf,
                                                      8192, 3072, 1024);
  flash_attn_kernel<<<dim3(64, 16), 256, 0, stream>>>(qkvbuf, vtbuf, aobuf);
  gemm_bt_kernel<1><<<dim3(8, 64), 256, 0, stream>>>(aobuf, woT, bo, out, nullptr,
                                                     8192, 1024, 1024);
}

// Round 3
// 296.307 us; speedup vs baseline: 1.0352x; 1.0352x over previous
//
#include <hip/hip_runtime.h>
#include <stdint.h>

typedef __attribute__((ext_vector_type(8))) short short8;
typedef __attribute__((ext_vector_type(4))) short short4v;
typedef __attribute__((ext_vector_type(4))) float floatx4;
typedef __attribute__((ext_vector_type(4))) _Float16 half4;
typedef __attribute__((ext_vector_type(2))) __fp16 pk2;

#define SEQ 2048
#define NTOK 8192
// 0.25 * log2(e): folds the 1/sqrt(H) quirk-scale and exp->exp2 into Q proj.
#define QSCALE 0.360673760222241f

#define MFMA16F16(a,b,c) __builtin_amdgcn_mfma_f32_16x16x16f16((a),(b),(c),0,0,0)

__device__ __forceinline__ float b2f(unsigned short u){
  union { unsigned int i; float f; } v; v.i = ((unsigned int)u) << 16; return v.f;
}
__device__ __forceinline__ unsigned short f2b(float f){
  union { float f; unsigned int i; } v; v.f = f;
  unsigned int r = v.i + 0x7fffu + ((v.i >> 16) & 1u);
  return (unsigned short)(r >> 16);
}
// async global->LDS, 16B per lane. Dest = wave-uniform base + lane*16.
__device__ __forceinline__ void async16(const unsigned short* g, unsigned short* l){
  __builtin_amdgcn_global_load_lds(
      (const __attribute__((address_space(1))) unsigned int*)g,
      (__attribute__((address_space(3))) unsigned int*)l, 16, 0, 0);
}

// ---------- fused prep: convert_x | transpose_w | bias_concat --------------
__global__ __launch_bounds__(256) void prep_kernel(
    const float* __restrict__ x,
    const float* __restrict__ wq, const float* __restrict__ wk,
    const float* __restrict__ wv, const float* __restrict__ wo,
    const float* __restrict__ bq, const float* __restrict__ bk,
    const float* __restrict__ bv,
    unsigned short* __restrict__ xb,
    unsigned short* __restrict__ wqkvT, unsigned short* __restrict__ woT,
    float* __restrict__ bqkv)
{
  __shared__ unsigned short lT[64][72];
  const int bid = blockIdx.x;
  const int tid = threadIdx.x;
  if (bid < 8192){
    int i = (bid*256 + tid)*4;
    float4 v = *(const float4*)(x + i);
    short4v o;
    o[0] = (short)f2b(v.x); o[1] = (short)f2b(v.y);
    o[2] = (short)f2b(v.z); o[3] = (short)f2b(v.w);
    *(short4v*)(xb + i) = o;
  } else if (bid < 9216){
    int idx = bid - 8192;
    int sel = idx >> 8, rest = idx & 255;
    const float* src = (sel==0)?wq:(sel==1)?wk:(sel==2)?wv:wo;
    unsigned short* dst = (sel<3) ? (wqkvT + (size_t)sel*1024*1024) : woT;
    int n0 = (rest & 15) * 64, k0 = (rest >> 4) * 64;
#pragma unroll
    for (int i=0;i<4;i++){
      int ch = tid + i*256;
      int r = ch>>4, c = (ch&15)*4;
      float4 v = *(const float4*)(src + (size_t)(k0+r)*1024 + n0 + c);
      lT[r][c+0] = f2b(v.x); lT[r][c+1] = f2b(v.y);
      lT[r][c+2] = f2b(v.z); lT[r][c+3] = f2b(v.w);
    }
    __syncthreads();
#pragma unroll
    for (int i=0;i<2;i++){
      int ch = tid + i*256;
      int rn = ch>>3, c = (ch&7)*8;
      short8 v;
#pragma unroll
      for (int j=0;j<8;j++) v[j] = (short)lT[c+j][rn];
      *(short8*)(dst + (size_t)(n0+rn)*1024 + k0 + c) = v;
    }
  } else {
    int i = (bid - 9216)*256 + tid;
    if (i < 3072){
      int sel = i >> 10, j = i & 1023;
      bqkv[i] = (sel==0)?bq[j]:(sel==1)?bk[j]:bv[j];
    }
  }
}

// ---------------- GEMM: C(MxN) = A(MxK) @ Bt(NxK)^T + bias ----------------
// MODE 1: f32 store. MODE 3: QKV fused — cols<1024 bf16*QSCALE, 1024..2047
// bf16, >=2048 (V) written f16 TRANSPOSED into Vt[(b*16+h)*64+dv][s]
// (fuses the old transpose_v kernel into the epilogue; V never hits qkvbuf).
template<int MODE>
__global__ __launch_bounds__(256) void gemm_bt_kernel(
    const unsigned short* __restrict__ A,
    const unsigned short* __restrict__ Bt,
    const float* __restrict__ bias,
    void* __restrict__ Cv,
    unsigned short* __restrict__ Vt,
    int M, int N, int K)
{
  __shared__ unsigned short lA[128*64];
  __shared__ unsigned short lB[128*64];
  const int tid  = threadIdx.x;
  const int lane = tid & 63;
  const int wave = tid >> 6;
  const int quad = lane >> 4;
  const int l15  = lane & 15;
  const int wR = (wave >> 1) * 64;
  const int wC = (wave & 1) * 64;
  const int rowB = blockIdx.y * 128;
  const int colB = blockIdx.x * 128;

  const int srow = wave*32 + (lane>>3);
  const int sc8  = (lane&7) ^ (lane>>3);
  const unsigned short* gA = A  + (size_t)(rowB + srow)*K + sc8*8;
  const unsigned short* gB = Bt + (size_t)(colB + srow)*K + sc8*8;
  unsigned short* lAw = lA + wave*32*64 + lane*8;
  unsigned short* lBw = lB + wave*32*64 + lane*8;

  floatx4 acc[4][4];
#pragma unroll
  for (int t=0;t<4;t++)
#pragma unroll
    for (int u=0;u<4;u++) acc[t][u] = (floatx4){0.f,0.f,0.f,0.f};

  for (int kt = 0; kt < K; kt += 64){
    __syncthreads();
#pragma unroll
    for (int i=0;i<4;i++){
      async16(gA + (size_t)i*8*K + kt, lAw + i*512);
      async16(gB + (size_t)i*8*K + kt, lBw + i*512);
    }
    __syncthreads();
#pragma unroll
    for (int ks=0; ks<2; ks++){
      const int cph = ((ks*4 + quad) ^ (l15 & 7)) * 8;
      short8 af[4], bf[4];
#pragma unroll
      for (int t=0;t<4;t++) af[t] = *(const short8*)&lA[(wR + t*16 + l15)*64 + cph];
#pragma unroll
      for (int u=0;u<4;u++) bf[u] = *(const short8*)&lB[(wC + u*16 + l15)*64 + cph];
#pragma unroll
      for (int t=0;t<4;t++)
#pragma unroll
        for (int u=0;u<4;u++)
          acc[t][u] = __builtin_amdgcn_mfma_f32_16x16x32_bf16(af[t], bf[u], acc[t][u], 0, 0, 0);
    }
  }
  // epilogue: C/D layout col = lane&15, row = quad*4 + r  [m89/m91 verified]
  if (MODE == 3 && colB >= 2048){
    // V block: transposed f16 store, 4 consecutive tokens per 8B chunk
#pragma unroll
    for (int u=0;u<4;u++){
      int col = colB + wC + u*16 + l15;
      float bval = bias[col];
      int vcol = col - 2048;
      int hh = vcol >> 6, dv = vcol & 63;
#pragma unroll
      for (int t=0;t<4;t++){
        int row0 = rowB + wR + t*16 + quad*4;       // token of acc[t][u][0]
        int bb = row0 >> 11, s = row0 & 2047;
        union { pk2 p[2]; short4v s4; } cv;
        cv.p[0] = __builtin_amdgcn_cvt_pkrtz(acc[t][u][0]+bval, acc[t][u][1]+bval);
        cv.p[1] = __builtin_amdgcn_cvt_pkrtz(acc[t][u][2]+bval, acc[t][u][3]+bval);
        *(short4v*)(Vt + ((size_t)(bb*16+hh)*64 + dv)*2048 + s) = cv.s4;
      }
    }
  } else {
#pragma unroll
    for (int u=0;u<4;u++){
      int col = colB + wC + u*16 + l15;
      float bval = bias[col];
      float scale = (MODE == 3 && col < 1024) ? QSCALE : 1.0f;
#pragma unroll
      for (int t=0;t<4;t++){
        int row0 = rowB + wR + t*16 + quad*4;
#pragma unroll
        for (int r=0;r<4;r++){
          float val = (acc[t][u][r] + bval) * scale;
          if (MODE == 1) ((float*)Cv)[(size_t)(row0 + r)*N + col] = val;
          else ((unsigned short*)Cv)[(size_t)(row0 + r)*N + col] = f2b(val);
        }
      }
    }
  }
}

// ---------------- flash attention forward, S^T formulation -----------------
// KV tile = 128 staged per barrier pair (two 64-row compute halves). Register
// prefetch of next tile during compute (measured-best staging).
//
// Round-3 revision: combine the two HW-verified-good halves of R0/R2.
//  * sigma-permuted V (R0): kv -> logical col with middle 2-bit fields
//    swapped (kv = c16*16+q4*4+j stored at col q4*16+c16*4+j). PV B-frag is
//    ONE b128 read per (v,hh) covering u=2hh,2hh+1 — half the ds_read count
//    of R2's per-u b64 form (whose 4-way alias cost exactly 2 extra
//    cyc/instr = the measured 4.19e6 conflicts).
//  * XOR-chunk swizzle (R2, HW-verified 0 conflicts on kf/staging): physical
//    16B chunk = logical chunk ^ (row&7), unpadded [64][64]. Phase analysis
//    (8-lane groups): PV b128 pchunk = (2*quad+hh)^l7 -> 8 distinct chunks =
//    all 32 banks; V staging b64 writes cover 16 disjoint bank pairs.
//  * s_setprio(1) around MFMA bursts (T5, m191 attn regime).
__global__ __launch_bounds__(256) void flash_attn_kernel(
    const unsigned short* __restrict__ qkv,
    const unsigned short* __restrict__ vt,      // f16 bits, [bh*64+dv][token]
    unsigned short* __restrict__ attn_out)      // bf16
{
  __shared__ __align__(16) unsigned short sK [2][64][64];  // bf16 [half][kv][dk]
  __shared__ __align__(16) unsigned short sVt[2][64][64];  // f16  [half][dv][sigma(kv)]
  const int bh = blockIdx.x;
  const int b = bh >> 4, h = bh & 15;
  const int qt = blockIdx.y;
  const int tid = threadIdx.x;
  const int wave = tid >> 6;
  const int lane = tid & 63;
  const int quad = lane >> 4, l15 = lane & 15;
  const int tok0 = b*SEQ + qt*128;

  // Q B-fragments straight from global (n = q = l15, k contiguous)
  short8 qf[2][2];
#pragma unroll
  for (int t=0;t<2;t++)
#pragma unroll
    for (int ks=0;ks<2;ks++)
      qf[t][ks] = *(const short8*)(qkv + (size_t)(tok0 + wave*32 + t*16 + l15)*3072
                                   + h*64 + ks*32 + quad*8);

  floatx4 oacc[2][4];
  float psum[2] = {0.f, 0.f};
#pragma unroll
  for (int t=0;t<2;t++)
#pragma unroll
    for (int v=0;v<4;v++) oacc[t][v] = (floatx4){0.f,0.f,0.f,0.f};

  // staging geometry: 4 chunks/thread; chunk i: half HF=i>>1, row R, col C.
  // sK: logical chunk = chh&7, XOR row&7. sVt: sigma cols, XOR row&7.
  int R[4], C[4], HF[4], SWK[4], CLO[4], CHI[4];
#pragma unroll
  for (int i=0;i<4;i++){
    int chh = tid + (i&1)*256;
    R[i] = chh >> 3; C[i] = (chh & 7)*8; HF[i] = i >> 1;
    int r7 = R[i] & 7;
    SWK[i] = (((chh & 7) ^ r7) * 8);
    int U = C[i] >> 4, QD = (C[i] & 15) >> 2;       // U in 0..3, QD in {0,2}
    CLO[i] = ((((QD+0)*2 + (U>>1)) ^ r7) << 3) + (U&1)*4;
    CHI[i] = ((((QD+1)*2 + (U>>1)) ^ r7) << 3) + (U&1)*4;
  }
  short8 rk[4], rv[4];
  // prefetch tile 0
#pragma unroll
  for (int i=0;i<4;i++){
    rk[i] = *(const short8*)(qkv + (size_t)(b*SEQ + HF[i]*64 + R[i])*3072 + 1024 + h*64 + C[i]);
    rv[i] = *(const short8*)(vt  + (size_t)(bh*64 + R[i])*2048 + HF[i]*64 + C[i]);
  }

  for (int it = 0; it < SEQ/128; it++){
    __syncthreads();
#pragma unroll
    for (int i=0;i<4;i++){
      *(short8*)&sK[HF[i]][R[i]][SWK[i]] = rk[i];
      short4v lo = {rv[i][0],rv[i][1],rv[i][2],rv[i][3]};
      short4v hi = {rv[i][4],rv[i][5],rv[i][6],rv[i][7]};
      *(short4v*)&sVt[HF[i]][R[i]][CLO[i]] = lo;
      *(short4v*)&sVt[HF[i]][R[i]][CHI[i]] = hi;
    }
    __syncthreads();
    if (it + 1 < SEQ/128){             // prefetch next 128-KV tile
      int nx = (it + 1) * 128;
#pragma unroll
      for (int i=0;i<4;i++){
        rk[i] = *(const short8*)(qkv + (size_t)(b*SEQ + nx + HF[i]*64 + R[i])*3072 + 1024 + h*64 + C[i]);
        rv[i] = *(const short8*)(vt  + (size_t)(bh*64 + R[i])*2048 + nx + HF[i]*64 + C[i]);
      }
    }

#pragma unroll
    for (int hf=0; hf<2; hf++){
      // S^T[kv][q]: A = K (m=kv), B = Q (n=q). C: row=kv local, col=q=l15.
      floatx4 sacc[4][2];
#pragma unroll
      for (int u=0;u<4;u++)
#pragma unroll
        for (int t=0;t<2;t++) sacc[u][t] = (floatx4){0.f,0.f,0.f,0.f};
#pragma unroll
      for (int ks=0;ks<2;ks++){
        short8 kf[4];
#pragma unroll
        for (int u=0;u<4;u++)
          kf[u] = *(const short8*)&sK[hf][u*16 + l15][((ks*4 + quad) ^ (l15 & 7)) * 8];
        __builtin_amdgcn_s_setprio(1);
#pragma unroll
        for (int u=0;u<4;u++)
#pragma unroll
          for (int t=0;t<2;t++)
            sacc[u][t] = __builtin_amdgcn_mfma_f32_16x16x32_bf16(kf[u], qf[t][ks], sacc[u][t], 0,0,0);
        __builtin_amdgcn_s_setprio(0);
      }

      // p = 2^s in-register; pack to f16 A-frags (k local = quad*4 + r):
      // x16 A-frag layout matches the S^T epilogue EXACTLY — no routing.
      half4 pf[4][2];
#pragma unroll
      for (int t=0;t<2;t++){
#pragma unroll
        for (int u=0;u<4;u++){
          float p0 = __builtin_amdgcn_exp2f(sacc[u][t][0]);
          float p1 = __builtin_amdgcn_exp2f(sacc[u][t][1]);
          float p2 = __builtin_amdgcn_exp2f(sacc[u][t][2]);
          float p3 = __builtin_amdgcn_exp2f(sacc[u][t][3]);
          psum[t] += (p0+p1)+(p2+p3);
          union { pk2 p2v[2]; half4 h4; } cv;
          cv.p2v[0] = __builtin_amdgcn_cvt_pkrtz(p0,p1);
          cv.p2v[1] = __builtin_amdgcn_cvt_pkrtz(p2,p3);
          pf[u][t] = cv.h4;
        }
      }

      // O[q][dv] += P V : sigma layout -> one b128 per (v,hh) pair, at
      // physical chunk (2*quad+hh) ^ (row&7 = l15&7). Conflict-free.
#pragma unroll
      for (int v=0;v<4;v++){
        half4 vf[4];
#pragma unroll
        for (int hh=0;hh<2;hh++){
          short8 w = *(const short8*)&sVt[hf][v*16 + l15]
                       [(((quad<<1) + hh) ^ (l15 & 7)) << 3];
          union { short4v s; half4 h; } a, bb;
          a.s  = (short4v){w[0],w[1],w[2],w[3]};
          bb.s = (short4v){w[4],w[5],w[6],w[7]};
          vf[2*hh]   = a.h;
          vf[2*hh+1] = bb.h;
        }
        __builtin_amdgcn_s_setprio(1);
#pragma unroll
        for (int t=0;t<2;t++)
#pragma unroll
          for (int u=0;u<4;u++)
            oacc[t][v] = MFMA16F16(pf[u][t], vf[u], oacc[t][v]);
        __builtin_amdgcn_s_setprio(0);
      }
    }
  }

  // final row-sum reduction: quads sharing l15 hold partials for q=l15
#pragma unroll
  for (int t=0;t<2;t++){
    float s = psum[t];
    s += __shfl_xor(s, 16);
    s += __shfl_xor(s, 32);
    psum[t] = s;
  }
  // epilogue: O rows are q local = quad*4+r; lsum for that q lives at lane q
#pragma unroll
  for (int t=0;t<2;t++){
#pragma unroll
    for (int r=0;r<4;r++){
      float inv = 1.0f / __shfl(psum[t], quad*4 + r);
      int tok = tok0 + wave*32 + t*16 + quad*4 + r;
#pragma unroll
      for (int v=0;v<4;v++)
        attn_out[(size_t)tok*1024 + h*64 + v*16 + l15] = f2b(oacc[t][v][r] * inv);
    }
  }
}

extern "C" void kernel_launch(void* const* d_in, const int* in_sizes, int n_in,
                              void* d_out, int out_size, void* d_ws, size_t ws_size,
                              hipStream_t stream)
{
  const float* x  = (const float*)d_in[0];
  const float* wq = (const float*)d_in[1];
  const float* bq = (const float*)d_in[2];
  const float* wk = (const float*)d_in[3];
  const float* bk = (const float*)d_in[4];
  const float* wv = (const float*)d_in[5];
  const float* bv = (const float*)d_in[6];
  const float* wo = (const float*)d_in[7];
  const float* bo = (const float*)d_in[8];
  float* out = (float*)d_out;

  char* ws = (char*)d_ws;
  unsigned short* wqkvT  = (unsigned short*)(ws);               // 3072x1024 bf16
  unsigned short* woT    = (unsigned short*)(ws + 6291456);     // 1024x1024 bf16
  float*          bqkv   = (float*)(ws + 8388608);              // 3072 f32
  unsigned short* xb     = (unsigned short*)(ws + 8400896);     // 8192x1024 bf16
  unsigned short* qkvbuf = (unsigned short*)(ws + 25178112);    // 8192x3072 bf16 (V region unused)
  unsigned short* vtbuf  = (unsigned short*)(ws + 75509760);    // 4096x2048 f16
  unsigned short* aobuf  = (unsigned short*)(ws + 92286976);    // 8192x1024 bf16

  prep_kernel<<<dim3(9228), 256, 0, stream>>>(x, wq, wk, wv, wo, bq, bk, bv,
                                              xb, wqkvT, woT, bqkv);
  gemm_bt_kernel<3><<<dim3(24, 64), 256, 0, stream>>>(xb, wqkvT, bqkv, qkvbuf, vtbuf,
                                                      8192, 3072, 1024);
  flash_attn_kernel<<<dim3(64, 16), 256, 0, stream>>>(qkvbuf, vtbuf, aobuf);
  gemm_bt_kernel<1><<<dim3(8, 64), 256, 0, stream>>>(aobuf, woT, bo, out, nullptr,
                                                     8192, 1024, 1024);
}

// Round 6
// 295.516 us; speedup vs baseline: 1.0380x; 1.0027x over previous
//
#include <hip/hip_runtime.h>
#include <stdint.h>

typedef __attribute__((ext_vector_type(8))) short short8;
typedef __attribute__((ext_vector_type(4))) short short4v;
typedef __attribute__((ext_vector_type(4))) float floatx4;
typedef __attribute__((ext_vector_type(8))) _Float16 half8;
typedef __attribute__((ext_vector_type(2))) __fp16 pk2;

#define SEQ 2048
#define NTOK 8192
// 0.25 * log2(e): folds the 1/sqrt(H) quirk-scale and exp->exp2 into Q proj.
#define QSCALE 0.360673760222241f

__device__ __forceinline__ float b2f(unsigned short u){
  union { unsigned int i; float f; } v; v.i = ((unsigned int)u) << 16; return v.f;
}
__device__ __forceinline__ unsigned short f2b(float f){
  union { float f; unsigned int i; } v; v.f = f;
  unsigned int r = v.i + 0x7fffu + ((v.i >> 16) & 1u);
  return (unsigned short)(r >> 16);
}
// async global->LDS, 16B per lane. Dest = wave-uniform base + lane*16.
__device__ __forceinline__ void async16(const unsigned short* g, unsigned short* l){
  __builtin_amdgcn_global_load_lds(
      (const __attribute__((address_space(1))) unsigned int*)g,
      (__attribute__((address_space(3))) unsigned int*)l, 16, 0, 0);
}

// ---------- fused prep: convert_x | transpose_w | bias_concat --------------
__global__ __launch_bounds__(256) void prep_kernel(
    const float* __restrict__ x,
    const float* __restrict__ wq, const float* __restrict__ wk,
    const float* __restrict__ wv, const float* __restrict__ wo,
    const float* __restrict__ bq, const float* __restrict__ bk,
    const float* __restrict__ bv,
    unsigned short* __restrict__ xb,
    unsigned short* __restrict__ wqkvT, unsigned short* __restrict__ woT,
    float* __restrict__ bqkv)
{
  __shared__ unsigned short lT[64][72];
  const int bid = blockIdx.x;
  const int tid = threadIdx.x;
  if (bid < 8192){
    int i = (bid*256 + tid)*4;
    float4 v = *(const float4*)(x + i);
    short4v o;
    o[0] = (short)f2b(v.x); o[1] = (short)f2b(v.y);
    o[2] = (short)f2b(v.z); o[3] = (short)f2b(v.w);
    *(short4v*)(xb + i) = o;
  } else if (bid < 9216){
    int idx = bid - 8192;
    int sel = idx >> 8, rest = idx & 255;
    const float* src = (sel==0)?wq:(sel==1)?wk:(sel==2)?wv:wo;
    unsigned short* dst = (sel<3) ? (wqkvT + (size_t)sel*1024*1024) : woT;
    int n0 = (rest & 15) * 64, k0 = (rest >> 4) * 64;
#pragma unroll
    for (int i=0;i<4;i++){
      int ch = tid + i*256;
      int r = ch>>4, c = (ch&15)*4;
      float4 v = *(const float4*)(src + (size_t)(k0+r)*1024 + n0 + c);
      lT[r][c+0] = f2b(v.x); lT[r][c+1] = f2b(v.y);
      lT[r][c+2] = f2b(v.z); lT[r][c+3] = f2b(v.w);
    }
    __syncthreads();
#pragma unroll
    for (int i=0;i<2;i++){
      int ch = tid + i*256;
      int rn = ch>>3, c = (ch&7)*8;
      short8 v;
#pragma unroll
      for (int j=0;j<8;j++) v[j] = (short)lT[c+j][rn];
      *(short8*)(dst + (size_t)(n0+rn)*1024 + k0 + c) = v;
    }
  } else {
    int i = (bid - 9216)*256 + tid;
    if (i < 3072){
      int sel = i >> 10, j = i & 1023;
      bqkv[i] = (sel==0)?bq[j]:(sel==1)?bk[j]:bv[j];
    }
  }
}

// ---------------- GEMM: C(MxN) = A(MxK) @ Bt(NxK)^T + bias ----------------
// MODE 1: f32 store. MODE 3: QKV fused — cols<1024 bf16*QSCALE, 1024..2047
// bf16, >=2048 (V) written f16 TRANSPOSED into Vt[(b*16+h)*64+dv][s]
// (fuses the old transpose_v kernel into the epilogue; V never hits qkvbuf).
template<int MODE>
__global__ __launch_bounds__(256) void gemm_bt_kernel(
    const unsigned short* __restrict__ A,
    const unsigned short* __restrict__ Bt,
    const float* __restrict__ bias,
    void* __restrict__ Cv,
    unsigned short* __restrict__ Vt,
    int M, int N, int K)
{
  __shared__ unsigned short lA[128*64];
  __shared__ unsigned short lB[128*64];
  const int tid  = threadIdx.x;
  const int lane = tid & 63;
  const int wave = tid >> 6;
  const int quad = lane >> 4;
  const int l15  = lane & 15;
  const int wR = (wave >> 1) * 64;
  const int wC = (wave & 1) * 64;
  const int rowB = blockIdx.y * 128;
  const int colB = blockIdx.x * 128;

  const int srow = wave*32 + (lane>>3);
  const int sc8  = (lane&7) ^ (lane>>3);
  const unsigned short* gA = A  + (size_t)(rowB + srow)*K + sc8*8;
  const unsigned short* gB = Bt + (size_t)(colB + srow)*K + sc8*8;
  unsigned short* lAw = lA + wave*32*64 + lane*8;
  unsigned short* lBw = lB + wave*32*64 + lane*8;

  floatx4 acc[4][4];
#pragma unroll
  for (int t=0;t<4;t++)
#pragma unroll
    for (int u=0;u<4;u++) acc[t][u] = (floatx4){0.f,0.f,0.f,0.f};

  for (int kt = 0; kt < K; kt += 64){
    __syncthreads();
#pragma unroll
    for (int i=0;i<4;i++){
      async16(gA + (size_t)i*8*K + kt, lAw + i*512);
      async16(gB + (size_t)i*8*K + kt, lBw + i*512);
    }
    __syncthreads();
#pragma unroll
    for (int ks=0; ks<2; ks++){
      const int cph = ((ks*4 + quad) ^ (l15 & 7)) * 8;
      short8 af[4], bf[4];
#pragma unroll
      for (int t=0;t<4;t++) af[t] = *(const short8*)&lA[(wR + t*16 + l15)*64 + cph];
#pragma unroll
      for (int u=0;u<4;u++) bf[u] = *(const short8*)&lB[(wC + u*16 + l15)*64 + cph];
#pragma unroll
      for (int t=0;t<4;t++)
#pragma unroll
        for (int u=0;u<4;u++)
          acc[t][u] = __builtin_amdgcn_mfma_f32_16x16x32_bf16(af[t], bf[u], acc[t][u], 0, 0, 0);
    }
  }
  // epilogue: C/D layout col = lane&15, row = quad*4 + r  [m89/m91 verified]
  if (MODE == 3 && colB >= 2048){
    // V block: transposed f16 store, 4 consecutive tokens per 8B chunk
#pragma unroll
    for (int u=0;u<4;u++){
      int col = colB + wC + u*16 + l15;
      float bval = bias[col];
      int vcol = col - 2048;
      int hh = vcol >> 6, dv = vcol & 63;
#pragma unroll
      for (int t=0;t<4;t++){
        int row0 = rowB + wR + t*16 + quad*4;       // token of acc[t][u][0]
        int bb = row0 >> 11, s = row0 & 2047;
        union { pk2 p[2]; short4v s4; } cv;
        cv.p[0] = __builtin_amdgcn_cvt_pkrtz(acc[t][u][0]+bval, acc[t][u][1]+bval);
        cv.p[1] = __builtin_amdgcn_cvt_pkrtz(acc[t][u][2]+bval, acc[t][u][3]+bval);
        *(short4v*)(Vt + ((size_t)(bb*16+hh)*64 + dv)*2048 + s) = cv.s4;
      }
    }
  } else {
#pragma unroll
    for (int u=0;u<4;u++){
      int col = colB + wC + u*16 + l15;
      float bval = bias[col];
      float scale = (MODE == 3 && col < 1024) ? QSCALE : 1.0f;
#pragma unroll
      for (int t=0;t<4;t++){
        int row0 = rowB + wR + t*16 + quad*4;
#pragma unroll
        for (int r=0;r<4;r++){
          float val = (acc[t][u][r] + bval) * scale;
          if (MODE == 1) ((float*)Cv)[(size_t)(row0 + r)*N + col] = val;
          else ((unsigned short*)Cv)[(size_t)(row0 + r)*N + col] = f2b(val);
        }
      }
    }
  }
}

// ---------------- flash attention forward, S^T formulation -----------------
// Round-6: full-rate x32 f16 PV with ZERO routing, via sigma-staged K rows.
//   The x32 PV A-frag needs lane(q=l15,quad) to hold P for kv=32B+8quad+j.
//   The S^T epilogue yields kv = sigma^-1(u*16+quad*4+r) — and sigma is OURS
//   to choose (relabeling S rows is free: exp2 elementwise, psum agnostic,
//   PV re-pairs by the same labels). sigma(kv): bits (B,q,a,r)->(B,a,q,r),
//   i.e. K row kv stored at LDS row (kv&32)|((kv&4)<<2)|((kv>>1)&12)|(kv&3).
//   Then sacc[u=2B+a][t] reg r holds kv = 32B+8quad+4a+r, so
//   pf[t][B] = {pack(sacc[2B][t]), pack(sacc[2B+1][t])} — fully in-lane.
// Everything else is the R1-PASSED structure (hardware-verified): x32 bf16
// QK^T, x32 f16 PV B-frag read (one b128 per (v,B)), XOR-chunk [64][64] LDS
// (zero conflicts), linear V staging, same epilogue. No setprio.
__global__ __launch_bounds__(256) void flash_attn_kernel(
    const unsigned short* __restrict__ qkv,
    const unsigned short* __restrict__ vt,      // f16 bits, [bh*64+dv][token]
    unsigned short* __restrict__ attn_out)      // bf16
{
  __shared__ __align__(16) unsigned short sK [2][64][64];  // bf16 [half][sigma(kv)][dk]
  __shared__ __align__(16) unsigned short sVt[2][64][64];  // f16  [half][dv][kv]
  const int bh = blockIdx.x;
  const int b = bh >> 4, h = bh & 15;
  const int qt = blockIdx.y;
  const int tid = threadIdx.x;
  const int wave = tid >> 6;
  const int lane = tid & 63;
  const int quad = lane >> 4, l15 = lane & 15;
  const int tok0 = b*SEQ + qt*128;

  // Q B-fragments straight from global (n = q = l15, k contiguous)
  short8 qf[2][2];
#pragma unroll
  for (int t=0;t<2;t++)
#pragma unroll
    for (int ks=0;ks<2;ks++)
      qf[t][ks] = *(const short8*)(qkv + (size_t)(tok0 + wave*32 + t*16 + l15)*3072
                                   + h*64 + ks*32 + quad*8);

  floatx4 oacc[2][4];
  float psum[2] = {0.f, 0.f};
#pragma unroll
  for (int t=0;t<2;t++)
#pragma unroll
    for (int v=0;v<4;v++) oacc[t][v] = (floatx4){0.f,0.f,0.f,0.f};

  // staging geometry: 4 chunks/thread; chunk i: half HF=i>>1, row R, col C.
  // K rows permuted by sigma at staging; chunk XOR keyed by PHYSICAL row.
  int R[4], C[4], HF[4], SR[4], SWK[4], SWV[4];
#pragma unroll
  for (int i=0;i<4;i++){
    int chh = tid + (i&1)*256;
    R[i] = chh >> 3; C[i] = (chh & 7)*8; HF[i] = i >> 1;
    SR[i] = (R[i]&32) | ((R[i]&4)<<2) | ((R[i]>>1)&12) | (R[i]&3);
    SWK[i] = (((chh & 7) ^ (SR[i] & 7)) * 8);
    SWV[i] = (((chh & 7) ^ (R[i]  & 7)) * 8);
  }
  short8 rk[4], rv[4];
  // prefetch tile 0
#pragma unroll
  for (int i=0;i<4;i++){
    rk[i] = *(const short8*)(qkv + (size_t)(b*SEQ + HF[i]*64 + R[i])*3072 + 1024 + h*64 + C[i]);
    rv[i] = *(const short8*)(vt  + (size_t)(bh*64 + R[i])*2048 + HF[i]*64 + C[i]);
  }

  for (int it = 0; it < SEQ/128; it++){
    __syncthreads();
#pragma unroll
    for (int i=0;i<4;i++){
      *(short8*)&sK [HF[i]][SR[i]][SWK[i]] = rk[i];
      *(short8*)&sVt[HF[i]][R[i] ][SWV[i]] = rv[i];
    }
    __syncthreads();
    if (it + 1 < SEQ/128){             // prefetch next 128-KV tile
      int nx = (it + 1) * 128;
#pragma unroll
      for (int i=0;i<4;i++){
        rk[i] = *(const short8*)(qkv + (size_t)(b*SEQ + nx + HF[i]*64 + R[i])*3072 + 1024 + h*64 + C[i]);
        rv[i] = *(const short8*)(vt  + (size_t)(bh*64 + R[i])*2048 + nx + HF[i]*64 + C[i]);
      }
    }

#pragma unroll
    for (int hf=0; hf<2; hf++){
      // S^T[srow][q]: A = K (m = sigma(kv)), B = Q (n = q = l15).
      floatx4 sacc[4][2];
#pragma unroll
      for (int u=0;u<4;u++)
#pragma unroll
        for (int t=0;t<2;t++) sacc[u][t] = (floatx4){0.f,0.f,0.f,0.f};
#pragma unroll
      for (int ks=0;ks<2;ks++){
        short8 kf[4];
#pragma unroll
        for (int u=0;u<4;u++)
          kf[u] = *(const short8*)&sK[hf][u*16 + l15][((ks*4 + quad) ^ (l15 & 7)) * 8];
#pragma unroll
        for (int u=0;u<4;u++)
#pragma unroll
          for (int t=0;t<2;t++)
            sacc[u][t] = __builtin_amdgcn_mfma_f32_16x16x32_bf16(kf[u], qf[t][ks], sacc[u][t], 0,0,0);
      }

      // p = 2^s; sacc[u][t] reg r holds kv = 32*(u>>1) + 8*quad + 4*(u&1) + r
      unsigned pw[4][2][2];
#pragma unroll
      for (int t=0;t<2;t++){
#pragma unroll
        for (int u=0;u<4;u++){
          float p0 = __builtin_amdgcn_exp2f(sacc[u][t][0]);
          float p1 = __builtin_amdgcn_exp2f(sacc[u][t][1]);
          float p2 = __builtin_amdgcn_exp2f(sacc[u][t][2]);
          float p3 = __builtin_amdgcn_exp2f(sacc[u][t][3]);
          psum[t] += (p0+p1)+(p2+p3);
          union { pk2 p; unsigned u32; } c0, c1;
          c0.p = __builtin_amdgcn_cvt_pkrtz(p0,p1);
          c1.p = __builtin_amdgcn_cvt_pkrtz(p2,p3);
          pw[u][t][0] = c0.u32; pw[u][t][1] = c1.u32;
        }
      }
      // x32 f16 A-frags: pf[t][B] elem j = P[q][kv=32B+8quad+j], in-lane
      half8 pf[2][2];
#pragma unroll
      for (int t=0;t<2;t++)
#pragma unroll
        for (int B=0;B<2;B++){
          union { unsigned u32[4]; half8 h; } a;
          a.u32[0] = pw[2*B  ][t][0]; a.u32[1] = pw[2*B  ][t][1];
          a.u32[2] = pw[2*B+1][t][0]; a.u32[3] = pw[2*B+1][t][1];
          pf[t][B] = a.h;
        }

      // O[q][dv] += P V : B-frag = V[kv=32B+8quad+j][dv=v*16+l15], one b128
#pragma unroll
      for (int v=0;v<4;v++){
#pragma unroll
        for (int B=0;B<2;B++){
          union { short8 s; half8 h; } vb;
          vb.s = *(const short8*)&sVt[hf][v*16 + l15][((B*4 + quad) ^ (l15 & 7)) * 8];
#pragma unroll
          for (int t=0;t<2;t++)
            oacc[t][v] = __builtin_amdgcn_mfma_f32_16x16x32_f16(pf[t][B], vb.h, oacc[t][v], 0,0,0);
        }
      }
    }
  }

  // final row-sum reduction: quads sharing l15 hold partials for q=l15
#pragma unroll
  for (int t=0;t<2;t++){
    float s = psum[t];
    s += __shfl_xor(s, 16);
    s += __shfl_xor(s, 32);
    psum[t] = s;
  }
  // epilogue: O rows are q local = quad*4+r; lsum for that q lives at lane q
#pragma unroll
  for (int t=0;t<2;t++){
#pragma unroll
    for (int r=0;r<4;r++){
      float inv = 1.0f / __shfl(psum[t], quad*4 + r);
      int tok = tok0 + wave*32 + t*16 + quad*4 + r;
#pragma unroll
      for (int v=0;v<4;v++)
        attn_out[(size_t)tok*1024 + h*64 + v*16 + l15] = f2b(oacc[t][v][r] * inv);
    }
  }
}

extern "C" void kernel_launch(void* const* d_in, const int* in_sizes, int n_in,
                              void* d_out, int out_size, void* d_ws, size_t ws_size,
                              hipStream_t stream)
{
  const float* x  = (const float*)d_in[0];
  const float* wq = (const float*)d_in[1];
  const float* bq = (const float*)d_in[2];
  const float* wk = (const float*)d_in[3];
  const float* bk = (const float*)d_in[4];
  const float* wv = (const float*)d_in[5];
  const float* bv = (const float*)d_in[6];
  const float* wo = (const float*)d_in[7];
  const float* bo = (const float*)d_in[8];
  float* out = (float*)d_out;

  char* ws = (char*)d_ws;
  unsigned short* wqkvT  = (unsigned short*)(ws);               // 3072x1024 bf16
  unsigned short* woT    = (unsigned short*)(ws + 6291456);     // 1024x1024 bf16
  float*          bqkv   = (float*)(ws + 8388608);              // 3072 f32
  unsigned short* xb     = (unsigned short*)(ws + 8400896);     // 8192x1024 bf16
  unsigned short* qkvbuf = (unsigned short*)(ws + 25178112);    // 8192x3072 bf16 (V region unused)
  unsigned short* vtbuf  = (unsigned short*)(ws + 75509760);    // 4096x2048 f16
  unsigned short* aobuf  = (unsigned short*)(ws + 92286976);    // 8192x1024 bf16

  prep_kernel<<<dim3(9228), 256, 0, stream>>>(x, wq, wk, wv, wo, bq, bk, bv,
                                              xb, wqkvT, woT, bqkv);
  gemm_bt_kernel<3><<<dim3(24, 64), 256, 0, stream>>>(xb, wqkvT, bqkv, qkvbuf, vtbuf,
                                                      8192, 3072, 1024);
  flash_attn_kernel<<<dim3(64, 16), 256, 0, stream>>>(qkvbuf, vtbuf, aobuf);
  gemm_bt_kernel<1><<<dim3(8, 64), 256, 0, stream>>>(aobuf, woT, bo, out, nullptr,
                                                     8192, 1024, 1024);
}

// Round 7
// 273.545 us; speedup vs baseline: 1.1214x; 1.0803x over previous
//
#include <hip/hip_runtime.h>
#include <stdint.h>

typedef __attribute__((ext_vector_type(8))) short short8;
typedef __attribute__((ext_vector_type(4))) short short4v;
typedef __attribute__((ext_vector_type(4))) float floatx4;
typedef __attribute__((ext_vector_type(8))) _Float16 half8;
typedef __attribute__((ext_vector_type(2))) __fp16 pk2;

#define SEQ 2048
#define NTOK 8192
// 0.25 * log2(e): folds the 1/sqrt(H) quirk-scale and exp->exp2 into Q proj.
#define QSCALE 0.360673760222241f

__device__ __forceinline__ float b2f(unsigned short u){
  union { unsigned int i; float f; } v; v.i = ((unsigned int)u) << 16; return v.f;
}
__device__ __forceinline__ unsigned short f2b(float f){
  union { float f; unsigned int i; } v; v.f = f;
  unsigned int r = v.i + 0x7fffu + ((v.i >> 16) & 1u);
  return (unsigned short)(r >> 16);
}
// async global->LDS, 16B per lane. Dest = wave-uniform base + lane*16.
__device__ __forceinline__ void async16(const unsigned short* g, unsigned short* l){
  __builtin_amdgcn_global_load_lds(
      (const __attribute__((address_space(1))) unsigned int*)g,
      (__attribute__((address_space(3))) unsigned int*)l, 16, 0, 0);
}

// ---------- fused prep: convert_x | transpose_w | bias_concat --------------
__global__ __launch_bounds__(256) void prep_kernel(
    const float* __restrict__ x,
    const float* __restrict__ wq, const float* __restrict__ wk,
    const float* __restrict__ wv, const float* __restrict__ wo,
    const float* __restrict__ bq, const float* __restrict__ bk,
    const float* __restrict__ bv,
    unsigned short* __restrict__ xb,
    unsigned short* __restrict__ wqkvT, unsigned short* __restrict__ woT,
    float* __restrict__ bqkv)
{
  __shared__ unsigned short lT[64][72];
  const int bid = blockIdx.x;
  const int tid = threadIdx.x;
  if (bid < 8192){
    int i = (bid*256 + tid)*4;
    float4 v = *(const float4*)(x + i);
    short4v o;
    o[0] = (short)f2b(v.x); o[1] = (short)f2b(v.y);
    o[2] = (short)f2b(v.z); o[3] = (short)f2b(v.w);
    *(short4v*)(xb + i) = o;
  } else if (bid < 9216){
    int idx = bid - 8192;
    int sel = idx >> 8, rest = idx & 255;
    const float* src = (sel==0)?wq:(sel==1)?wk:(sel==2)?wv:wo;
    unsigned short* dst = (sel<3) ? (wqkvT + (size_t)sel*1024*1024) : woT;
    int n0 = (rest & 15) * 64, k0 = (rest >> 4) * 64;
#pragma unroll
    for (int i=0;i<4;i++){
      int ch = tid + i*256;
      int r = ch>>4, c = (ch&15)*4;
      float4 v = *(const float4*)(src + (size_t)(k0+r)*1024 + n0 + c);
      lT[r][c+0] = f2b(v.x); lT[r][c+1] = f2b(v.y);
      lT[r][c+2] = f2b(v.z); lT[r][c+3] = f2b(v.w);
    }
    __syncthreads();
#pragma unroll
    for (int i=0;i<2;i++){
      int ch = tid + i*256;
      int rn = ch>>3, c = (ch&7)*8;
      short8 v;
#pragma unroll
      for (int j=0;j<8;j++) v[j] = (short)lT[c+j][rn];
      *(short8*)(dst + (size_t)(n0+rn)*1024 + k0 + c) = v;
    }
  } else {
    int i = (bid - 9216)*256 + tid;
    if (i < 3072){
      int sel = i >> 10, j = i & 1023;
      bqkv[i] = (sel==0)?bq[j]:(sel==1)?bk[j]:bv[j];
    }
  }
}

// ---------------- GEMM: C(MxN) = A(MxK) @ Bt(NxK)^T + bias ----------------
// MODE 1: f32 store. MODE 3: QKV fused — cols<1024 bf16*QSCALE, 1024..2047
// bf16, >=2048 (V) written f16 TRANSPOSED into Vt[(b*16+h)*64+dv][s]
// (fuses the old transpose_v kernel into the epilogue; V never hits qkvbuf).
template<int MODE>
__global__ __launch_bounds__(256) void gemm_bt_kernel(
    const unsigned short* __restrict__ A,
    const unsigned short* __restrict__ Bt,
    const float* __restrict__ bias,
    void* __restrict__ Cv,
    unsigned short* __restrict__ Vt,
    int M, int N, int K)
{
  __shared__ unsigned short lA[128*64];
  __shared__ unsigned short lB[128*64];
  const int tid  = threadIdx.x;
  const int lane = tid & 63;
  const int wave = tid >> 6;
  const int quad = lane >> 4;
  const int l15  = lane & 15;
  const int wR = (wave >> 1) * 64;
  const int wC = (wave & 1) * 64;
  const int rowB = blockIdx.y * 128;
  const int colB = blockIdx.x * 128;

  const int srow = wave*32 + (lane>>3);
  const int sc8  = (lane&7) ^ (lane>>3);
  const unsigned short* gA = A  + (size_t)(rowB + srow)*K + sc8*8;
  const unsigned short* gB = Bt + (size_t)(colB + srow)*K + sc8*8;
  unsigned short* lAw = lA + wave*32*64 + lane*8;
  unsigned short* lBw = lB + wave*32*64 + lane*8;

  floatx4 acc[4][4];
#pragma unroll
  for (int t=0;t<4;t++)
#pragma unroll
    for (int u=0;u<4;u++) acc[t][u] = (floatx4){0.f,0.f,0.f,0.f};

  for (int kt = 0; kt < K; kt += 64){
    __syncthreads();
#pragma unroll
    for (int i=0;i<4;i++){
      async16(gA + (size_t)i*8*K + kt, lAw + i*512);
      async16(gB + (size_t)i*8*K + kt, lBw + i*512);
    }
    __syncthreads();
#pragma unroll
    for (int ks=0; ks<2; ks++){
      const int cph = ((ks*4 + quad) ^ (l15 & 7)) * 8;
      short8 af[4], bf[4];
#pragma unroll
      for (int t=0;t<4;t++) af[t] = *(const short8*)&lA[(wR + t*16 + l15)*64 + cph];
#pragma unroll
      for (int u=0;u<4;u++) bf[u] = *(const short8*)&lB[(wC + u*16 + l15)*64 + cph];
#pragma unroll
      for (int t=0;t<4;t++)
#pragma unroll
        for (int u=0;u<4;u++)
          acc[t][u] = __builtin_amdgcn_mfma_f32_16x16x32_bf16(af[t], bf[u], acc[t][u], 0, 0, 0);
    }
  }
  // epilogue: C/D layout col = lane&15, row = quad*4 + r  [m89/m91 verified]
  if (MODE == 3 && colB >= 2048){
    // V block: transposed f16 store, 4 consecutive tokens per 8B chunk
#pragma unroll
    for (int u=0;u<4;u++){
      int col = colB + wC + u*16 + l15;
      float bval = bias[col];
      int vcol = col - 2048;
      int hh = vcol >> 6, dv = vcol & 63;
#pragma unroll
      for (int t=0;t<4;t++){
        int row0 = rowB + wR + t*16 + quad*4;       // token of acc[t][u][0]
        int bb = row0 >> 11, s = row0 & 2047;
        union { pk2 p[2]; short4v s4; } cv;
        cv.p[0] = __builtin_amdgcn_cvt_pkrtz(acc[t][u][0]+bval, acc[t][u][1]+bval);
        cv.p[1] = __builtin_amdgcn_cvt_pkrtz(acc[t][u][2]+bval, acc[t][u][3]+bval);
        *(short4v*)(Vt + ((size_t)(bb*16+hh)*64 + dv)*2048 + s) = cv.s4;
      }
    }
  } else {
#pragma unroll
    for (int u=0;u<4;u++){
      int col = colB + wC + u*16 + l15;
      float bval = bias[col];
      float scale = (MODE == 3 && col < 1024) ? QSCALE : 1.0f;
#pragma unroll
      for (int t=0;t<4;t++){
        int row0 = rowB + wR + t*16 + quad*4;
#pragma unroll
        for (int r=0;r<4;r++){
          float val = (acc[t][u][r] + bval) * scale;
          if (MODE == 1) ((float*)Cv)[(size_t)(row0 + r)*N + col] = val;
          else ((unsigned short*)Cv)[(size_t)(row0 + r)*N + col] = f2b(val);
        }
      }
    }
  }
}

// ---------------- flash attention forward, S^T formulation -----------------
// Round-7: same verified math as R6 (sigma-staged K -> in-lane full-rate x32
// f16 PV; XOR-chunk swizzled LDS, zero conflicts). Structural changes only:
//  * QBLK=256 (8 waves/block, grid 64x8): each staged KV tile serves 2x the
//    q-rows -> chip-wide staging work (prefetch issues, ds_writes, barriers,
//    KV re-reads) HALVES. Per-wave compute identical.
//  * True LDS double-buffer (64KB, 2 blocks/CU): write tile t -> buf[t&1]
//    BEFORE the barrier, compute after; tile t+1 writes the other buffer.
//    ONE barrier per tile (16 vs 32). Safety: a wave at W(t+2) has passed
//    barrier(t+1), which requires all waves finished W(t+1), which follows
//    C(t) in program order — so no wave can still be reading buf[t&1].
//  * Prefetch global loads issued AFTER the barrier (syncthreads drains
//    vmcnt(0) — loads issued before it would lose their async overlap).
__global__ __launch_bounds__(512) void flash_attn_kernel(
    const unsigned short* __restrict__ qkv,
    const unsigned short* __restrict__ vt,      // f16 bits, [bh*64+dv][token]
    unsigned short* __restrict__ attn_out)      // bf16
{
  __shared__ __align__(16) unsigned short sK [2][128][64];  // bf16 [buf][sigma(kv)][dk]
  __shared__ __align__(16) unsigned short sVt[2][64][128];  // f16  [buf][dv][kv]
  const int bh = blockIdx.x;
  const int b = bh >> 4, h = bh & 15;
  const int qt = blockIdx.y;
  const int tid = threadIdx.x;
  const int wave = tid >> 6;
  const int lane = tid & 63;
  const int quad = lane >> 4, l15 = lane & 15;
  const int tok0 = b*SEQ + qt*256;

  // Q B-fragments straight from global (n = q = l15, k contiguous)
  short8 qf[2][2];
#pragma unroll
  for (int t=0;t<2;t++)
#pragma unroll
    for (int ks=0;ks<2;ks++)
      qf[t][ks] = *(const short8*)(qkv + (size_t)(tok0 + wave*32 + t*16 + l15)*3072
                                   + h*64 + ks*32 + quad*8);

  floatx4 oacc[2][4];
  float psum[2] = {0.f, 0.f};
#pragma unroll
  for (int t=0;t<2;t++)
#pragma unroll
    for (int v=0;v<4;v++) oacc[t][v] = (floatx4){0.f,0.f,0.f,0.f};

  // staging descriptors: 2 K-chunks + 2 V-chunks per thread (512 threads).
  // K: 1024 short8-chunks of [128 kv][64 dk]; row sigma-permuted (bits 5,6
  // pass through), chunk XOR-swizzled by physical row &7.
  // V: 1024 chunks of [64 dv][128 kv]; low-3 chunk bits XOR row&7 (hf bit
  // passes through).
  const unsigned short* kbase[2]; const unsigned short* vbase[2];
  int KD[2], VD[2];
#pragma unroll
  for (int i=0;i<2;i++){
    int c = tid + i*512;
    int kr = c >> 3, kc = c & 7;
    int sr = (kr & 96) | ((kr & 4) << 2) | ((kr >> 1) & 12) | (kr & 3);
    kbase[i] = qkv + (size_t)(b*SEQ + kr)*3072 + 1024 + h*64 + kc*8;
    KD[i] = sr*64 + ((kc ^ (sr & 7)) * 8);
    int dv = c >> 4, vc = c & 15;
    int hfb = vc >> 3, c3 = vc & 7;
    vbase[i] = vt + (size_t)(bh*64 + dv)*2048 + vc*8;
    VD[i] = dv*128 + (hfb*8 + (c3 ^ (dv & 7))) * 8;
  }
  short8 rk[2], rv[2];
  // prefetch tile 0
#pragma unroll
  for (int i=0;i<2;i++){
    rk[i] = *(const short8*)(kbase[i]);
    rv[i] = *(const short8*)(vbase[i]);
  }

  for (int it = 0; it < SEQ/128; it++){
    unsigned short* sKb = &sK [it & 1][0][0];
    unsigned short* sVb = &sVt[it & 1][0][0];
#pragma unroll
    for (int i=0;i<2;i++){
      *(short8*)(sKb + KD[i]) = rk[i];
      *(short8*)(sVb + VD[i]) = rv[i];
    }
    __syncthreads();
    if (it + 1 < SEQ/128){             // issue next-tile loads (in flight
      int nx = (it + 1) * 128;         //  across the whole compute phase)
#pragma unroll
      for (int i=0;i<2;i++){
        rk[i] = *(const short8*)(kbase[i] + (size_t)nx*3072);
        rv[i] = *(const short8*)(vbase[i] + nx);
      }
    }

#pragma unroll
    for (int hf=0; hf<2; hf++){
      // S^T[srow][q]: A = K (m = sigma(kv)), B = Q (n = q = l15).
      floatx4 sacc[4][2];
#pragma unroll
      for (int u=0;u<4;u++)
#pragma unroll
        for (int t=0;t<2;t++) sacc[u][t] = (floatx4){0.f,0.f,0.f,0.f};
#pragma unroll
      for (int ks=0;ks<2;ks++){
        short8 kf[4];
#pragma unroll
        for (int u=0;u<4;u++)
          kf[u] = *(const short8*)(sKb + (hf*64 + u*16 + l15)*64
                                   + ((ks*4 + quad) ^ (l15 & 7)) * 8);
#pragma unroll
        for (int u=0;u<4;u++)
#pragma unroll
          for (int t=0;t<2;t++)
            sacc[u][t] = __builtin_amdgcn_mfma_f32_16x16x32_bf16(kf[u], qf[t][ks], sacc[u][t], 0,0,0);
      }

      // p = 2^s; sacc[u][t] reg r holds kv = 32*(u>>1) + 8*quad + 4*(u&1) + r
      unsigned pw[4][2][2];
#pragma unroll
      for (int t=0;t<2;t++){
#pragma unroll
        for (int u=0;u<4;u++){
          float p0 = __builtin_amdgcn_exp2f(sacc[u][t][0]);
          float p1 = __builtin_amdgcn_exp2f(sacc[u][t][1]);
          float p2 = __builtin_amdgcn_exp2f(sacc[u][t][2]);
          float p3 = __builtin_amdgcn_exp2f(sacc[u][t][3]);
          psum[t] += (p0+p1)+(p2+p3);
          union { pk2 p; unsigned u32; } c0, c1;
          c0.p = __builtin_amdgcn_cvt_pkrtz(p0,p1);
          c1.p = __builtin_amdgcn_cvt_pkrtz(p2,p3);
          pw[u][t][0] = c0.u32; pw[u][t][1] = c1.u32;
        }
      }
      // x32 f16 A-frags: pf[t][B] elem j = P[q][kv=32B+8quad+j], in-lane
      half8 pf[2][2];
#pragma unroll
      for (int t=0;t<2;t++)
#pragma unroll
        for (int B=0;B<2;B++){
          union { unsigned u32[4]; half8 h; } a;
          a.u32[0] = pw[2*B  ][t][0]; a.u32[1] = pw[2*B  ][t][1];
          a.u32[2] = pw[2*B+1][t][0]; a.u32[3] = pw[2*B+1][t][1];
          pf[t][B] = a.h;
        }

      // O[q][dv] += P V : B-frag = V[kv=32B+8quad+j][dv=v*16+l15], one b128
#pragma unroll
      for (int v=0;v<4;v++){
#pragma unroll
        for (int B=0;B<2;B++){
          union { short8 s; half8 h; } vb;
          vb.s = *(const short8*)(sVb + (v*16 + l15)*128
                                  + (hf*8 + ((B*4 + quad) ^ (l15 & 7))) * 8);
#pragma unroll
          for (int t=0;t<2;t++)
            oacc[t][v] = __builtin_amdgcn_mfma_f32_16x16x32_f16(pf[t][B], vb.h, oacc[t][v], 0,0,0);
        }
      }
    }
  }

  // final row-sum reduction: quads sharing l15 hold partials for q=l15
#pragma unroll
  for (int t=0;t<2;t++){
    float s = psum[t];
    s += __shfl_xor(s, 16);
    s += __shfl_xor(s, 32);
    psum[t] = s;
  }
  // epilogue: O rows are q local = quad*4+r; lsum for that q lives at lane q
#pragma unroll
  for (int t=0;t<2;t++){
#pragma unroll
    for (int r=0;r<4;r++){
      float inv = 1.0f / __shfl(psum[t], quad*4 + r);
      int tok = tok0 + wave*32 + t*16 + quad*4 + r;
#pragma unroll
      for (int v=0;v<4;v++)
        attn_out[(size_t)tok*1024 + h*64 + v*16 + l15] = f2b(oacc[t][v][r] * inv);
    }
  }
}

extern "C" void kernel_launch(void* const* d_in, const int* in_sizes, int n_in,
                              void* d_out, int out_size, void* d_ws, size_t ws_size,
                              hipStream_t stream)
{
  const float* x  = (const float*)d_in[0];
  const float* wq = (const float*)d_in[1];
  const float* bq = (const float*)d_in[2];
  const float* wk = (const float*)d_in[3];
  const float* bk = (const float*)d_in[4];
  const float* wv = (const float*)d_in[5];
  const float* bv = (const float*)d_in[6];
  const float* wo = (const float*)d_in[7];
  const float* bo = (const float*)d_in[8];
  float* out = (float*)d_out;

  char* ws = (char*)d_ws;
  unsigned short* wqkvT  = (unsigned short*)(ws);               // 3072x1024 bf16
  unsigned short* woT    = (unsigned short*)(ws + 6291456);     // 1024x1024 bf16
  float*          bqkv   = (float*)(ws + 8388608);              // 3072 f32
  unsigned short* xb     = (unsigned short*)(ws + 8400896);     // 8192x1024 bf16
  unsigned short* qkvbuf = (unsigned short*)(ws + 25178112);    // 8192x3072 bf16 (V region unused)
  unsigned short* vtbuf  = (unsigned short*)(ws + 75509760);    // 4096x2048 f16
  unsigned short* aobuf  = (unsigned short*)(ws + 92286976);    // 8192x1024 bf16

  prep_kernel<<<dim3(9228), 256, 0, stream>>>(x, wq, wk, wv, wo, bq, bk, bv,
                                              xb, wqkvT, woT, bqkv);
  gemm_bt_kernel<3><<<dim3(24, 64), 256, 0, stream>>>(xb, wqkvT, bqkv, qkvbuf, vtbuf,
                                                      8192, 3072, 1024);
  flash_attn_kernel<<<dim3(64, 8), 512, 0, stream>>>(qkvbuf, vtbuf, aobuf);
  gemm_bt_kernel<1><<<dim3(8, 64), 256, 0, stream>>>(aobuf, woT, bo, out, nullptr,
                                                     8192, 1024, 1024);
}